// Round 14
// baseline (283.752 us; speedup 1.0000x reference)
//
#include <hip/hip_runtime.h>
#include <hip/hip_bf16.h>
#include <stdint.h>

#define B_ 16
#define S_ 2048
#define D_ 512
#define TAU 0.1f
#define SCALE 0.04419417382415922f   // 1/sqrt(512)
#define BM 128
#define BN 32

typedef __attribute__((ext_vector_type(8))) __bf16 bf16x8;
typedef __attribute__((ext_vector_type(4))) float f32x4;
typedef __attribute__((ext_vector_type(16))) float f32x16;
typedef __attribute__((ext_vector_type(8))) uint16_t u16x8;
typedef __attribute__((ext_vector_type(4))) uint16_t u16x4;

__device__ __forceinline__ uint16_t f2bf(float f) {
  __hip_bfloat16 h = __float2bfloat16(f);
  return __builtin_bit_cast(uint16_t, h);
}

__device__ __forceinline__ float bf2f(uint16_t u) {
  return __uint_as_float(((uint32_t)u) << 16);
}

__device__ __forceinline__ void g2lds16(void* lds, const void* g) {
  __builtin_amdgcn_global_load_lds(
      (const __attribute__((address_space(1))) unsigned int*)g,
      (__attribute__((address_space(3))) unsigned int*)lds, 16, 0, 0);
}

// ---------------------------------------------------------------------------
// Convert fp32 x -> bf16 copies in ws (unchanged):
//  xbf[b][t][d]  row-major, 16B-granule index XOR-swizzled by (t&7)
//  xt [b][d][t]  row-major in t, granule low-2-bits XOR-swizzled by (d&3)
// ---------------------------------------------------------------------------
__global__ __launch_bounds__(256) void convert_kernel(
    const float* __restrict__ x, uint16_t* __restrict__ xbf,
    uint16_t* __restrict__ xt) {
  const int bid = blockIdx.x;
  const int b = bid >> 8;
  const int tt = (bid >> 3) & 31;
  const int dt = bid & 7;
  const int t0 = tt * 64, d0 = dt * 64;
  __shared__ uint16_t tile[64][72];
  const int tid = threadIdx.x;
  const float* xb = x + ((size_t)b * S_ + t0) * D_ + d0;

#pragma unroll
  for (int it = 0; it < 4; ++it) {
    int r = it * 16 + (tid >> 4);
    int c = (tid & 15) * 4;
    float4 v = *(const float4*)(xb + (size_t)r * D_ + c);
    tile[r][c + 0] = f2bf(v.x);
    tile[r][c + 1] = f2bf(v.y);
    tile[r][c + 2] = f2bf(v.z);
    tile[r][c + 3] = f2bf(v.w);
  }
  __syncthreads();

#pragma unroll
  for (int it = 0; it < 2; ++it) {
    int G = it * 256 + tid;
    int tl = G >> 3, gl = G & 7;
    int t = t0 + tl;
    int p = (d0 >> 3) + (gl ^ (t & 7));
    u16x8 v = *(const u16x8*)&tile[tl][gl * 8];
    *(u16x8*)((char*)xbf + (size_t)(b * S_ + t) * 1024 + p * 16) = v;
  }
#pragma unroll
  for (int it = 0; it < 2; ++it) {
    int G = it * 256 + tid;
    int dl = G >> 3, gl = G & 7;
    int d = d0 + dl;
    int p = (gl & ~3) | ((gl ^ (d & 3)) & 3);
    u16x8 v;
#pragma unroll
    for (int i = 0; i < 8; ++i) v[i] = tile[gl * 8 + i][dl];
    *(u16x8*)((char*)xt + (size_t)(b * D_ + d) * 4096 + t0 * 2 + p * 16) = v;
  }
}

// ---------------------------------------------------------------------------
// Kernel A (round-6, proven ~86us): S^T = K·Q^T via mfma 32x32x16;
// klds double-buffered; E written directly from acc registers.
// ---------------------------------------------------------------------------
__global__ __launch_bounds__(512, 2) void attn_scores(
    const uint16_t* __restrict__ xbf, uint16_t* __restrict__ E,
    float* __restrict__ psum_g) {
  __shared__ uint16_t klds[2][64 * 512];   // 2 x 64KB swizzled K-tile images
  __shared__ float redbuf[4 * 2 * 32];

  const int tid = threadIdx.x;
  const int wave = tid >> 6, lane = tid & 63;
  const int h = lane >> 5, l31 = lane & 31, l7 = lane & 7;
  const int qi = wave >> 1, ki = wave & 1;
  const int bid = blockIdx.x;
  const int job = (bid & 7) * 32 + (bid >> 3);
  const int b = job >> 4;
  const int q0 = (job & 15) * BM;

  const char* xb = (const char*)xbf + (size_t)b * S_ * 1024;

  const size_t qrow = (size_t)(q0 + qi * 32 + l31);
  bf16x8 qf[32];
#pragma unroll
  for (int s = 0; s < 32; ++s) {
    int g = (2 * s + h) ^ l7;  // qrow&7 == l7
    qf[s] = *(const bf16x8*)(xb + qrow * 1024 + g * 16);
  }

  float psum = 0.f;

  // prologue: stage tile 0
#pragma unroll
  for (int i = 0; i < 8; ++i) {
    int row = wave * 8 + i;
    g2lds16((char*)klds[0] + row * 1024, xb + (size_t)row * 1024 + lane * 16);
  }
  __syncthreads();

  for (int kt = 0; kt < 32; ++kt) {
    const int cur = kt & 1;
    const char* kldsc = (const char*)klds[cur];

    if (kt < 31) {
#pragma unroll
      for (int i = 0; i < 8; ++i) {
        int row = wave * 8 + i;
        g2lds16((char*)klds[cur ^ 1] + row * 1024,
                xb + (size_t)((kt + 1) * 64 + row) * 1024 + lane * 16);
      }
    }

    f32x16 acc = {};
#pragma unroll
    for (int s = 0; s < 32; ++s) {
      int g = (2 * s + h) ^ l7;  // klocal&7 == l7
      bf16x8 af = *(const bf16x8*)(kldsc + (size_t)(ki * 32 + l31) * 1024 + g * 16);
      acc = __builtin_amdgcn_mfma_f32_32x32x16_bf16(af, qf[s], acc, 0, 0, 0);
    }

    // E = exp(masked score), stored directly from regs.
    // acc[r]: q=l31 (col), k = ki*32 + (r&3) + 8*(r>>2) + 4h.
    uint16_t* ep = E + ((size_t)b * S_ + qrow) * 2048 + kt * 64 + ki * 32 + 4 * h;
#pragma unroll
    for (int q4 = 0; q4 < 4; ++q4) {
      u16x4 w4;
#pragma unroll
      for (int j = 0; j < 4; ++j) {
        float s = acc[4 * q4 + j] * SCALE;
        float e = (s > TAU) ? __expf(s) : 0.f;
        psum += e;
        w4[j] = f2bf(e);
      }
      *(u16x4*)(ep + 8 * q4) = w4;
    }
    __syncthreads();
  }

  psum += __shfl_xor(psum, 32, 64);
  if (lane < 32) redbuf[qi * 64 + ki * 32 + lane] = psum;
  __syncthreads();
  if (ki == 0 && lane < 32) {
    float tot = redbuf[qi * 64 + lane] + redbuf[qi * 64 + 32 + lane];
    psum_g[(size_t)b * S_ + q0 + qi * 32 + lane] = tot;
  }
}

// ---------------------------------------------------------------------------
// Kernel B v14 = pv10 with the mid-kt barrier REMOVED via wave-local wstage:
// wave (qi,di) writes its OWN 16 rows (lanes l31>>4==di) into slice qi and
// reads back exactly those rows for the full-line W store — within-wave
// LDS write->read needs only lgkmcnt (compiler-inserted), no __syncthreads.
// inv[row] via __shfl (invlds deleted). ONE barrier per kt (xt dbuf guard).
// Everything else byte-identical to pv10 (best measured, ~170us).
// ---------------------------------------------------------------------------
#define PV_KT_BODY(KT, XCUR, XNXT, BCUR, BNXT)                                  \
  do {                                                                          \
    if ((KT) < 31) {                                                            \
      /* prefetch next-kt E fragments (consumed next body) */                   \
      _Pragma("unroll") for (int ks = 0; ks < 4; ++ks)                          \
          BNXT[ks] = *(const bf16x8*)(Erow + ((KT) + 1) * 64 + 16 * ks);        \
      /* stage next xt tile into the other buffer */                            \
      _Pragma("unroll") for (int i = 0; i < 8; ++i) {                           \
        int d = wave * 64 + i * 8 + (lane >> 3);                                \
        int gd = l7 ^ (d & 7);                                                  \
        int p2 = (gd & ~3) | ((gd ^ (d & 3)) & 3);                              \
        g2lds16((char*)(XNXT) + (wave * 64 + i * 8) * 128,                      \
                xtb + (size_t)d * 4096 + ((KT) + 1) * 128 + p2 * 16);           \
      }                                                                         \
    }                                                                           \
    /* PV MFMAs: A = X^T[32d x 16k] from LDS, B = BCUR (prefetched) */          \
    _Pragma("unroll") for (int t = 0; t < 8; ++t) {                             \
      int dl = di * 256 + t * 32 + l31;                                         \
      _Pragma("unroll") for (int ks = 0; ks < 4; ++ks) {                        \
        int slot = (2 * ks + h) ^ (dl & 7);                                     \
        bf16x8 af =                                                             \
            *(const bf16x8*)((const char*)(XCUR) + (size_t)dl * 128 + slot * 16);\
        pv[t] = __builtin_amdgcn_mfma_f32_32x32x16_bf16(af, BCUR[ks], pv[t],    \
                                                        0, 0, 0);               \
      }                                                                         \
    }                                                                           \
    /* wave-local wstage write: own 16 rows only (l31>>4 == di), slice qi */    \
    if ((l31 >> 4) == di) {                                                     \
      _Pragma("unroll") for (int ks = 0; ks < 4; ++ks) {                        \
        int g = (2 * ks + h) ^ l7; /* (q&7)==l7 */                              \
        *(u16x8*)(wstc + qi * 4096 + l31 * 128 + g * 16) =                      \
            __builtin_bit_cast(u16x8, BCUR[ks]);                                \
      }                                                                         \
    }                                                                           \
    /* W = E*inv -> global; 8 rows x 128B full lines, rows rl=di*16+j*8+.. */   \
    _Pragma("unroll") for (int j = 0; j < 2; ++j) {                             \
      int rl = di * 16 + j * 8 + (lane >> 3);                                   \
      float invr = __shfl(inv, rl, 64);                                         \
      _Pragma("unroll") for (int hf = 0; hf < 2; ++hf) {                        \
        int g = (hf * 4 + (l7 >> 1)) ^ (rl & 7);                                \
        u16x4 ev = *(const u16x4*)(wstc + qi * 4096 + rl * 128 + g * 16 +       \
                                   (l7 & 1) * 8);                               \
        f32x4 w;                                                                \
        _Pragma("unroll") for (int i2 = 0; i2 < 4; ++i2)                        \
            w[i2] = bf2f(ev[i2]) * invr;                                        \
        *(f32x4*)(wout + ((size_t)(b * S_ + q0 + qi * 32 + rl)) * 2048 +        \
                  (KT) * 64 + hf * 32 + l7 * 4) = w;                            \
      }                                                                         \
    }                                                                           \
    __syncthreads();                                                            \
  } while (0)

__global__ __launch_bounds__(512) void attn_pv14(
    const uint16_t* __restrict__ E, const uint16_t* __restrict__ xt,
    const float* __restrict__ psum_g, float* __restrict__ ctx,
    float* __restrict__ wout) {
  __shared__ uint16_t xtlds[2][512 * 64];  // 2 x 64KB, granule-swizzled by d&7
  __shared__ uint16_t wstage[4 * 32 * 64]; // 16KB, slice per qi, wave-local

  const int tid = threadIdx.x;
  const int wave = tid >> 6, lane = tid & 63;
  const int h = lane >> 5, l31 = lane & 31, l7 = lane & 7;
  const int qi = wave >> 1, di = wave & 1;
  const int bid = blockIdx.x;
  const int job = (bid & 7) * 32 + (bid >> 3);
  const int b = job >> 4;
  const int q0 = (job & 15) * BM;

  const char* xtb = (const char*)xt + (size_t)b * D_ * 4096;
  char* wstc = (char*)wstage;

  const float inv = 1.0f / psum_g[(size_t)b * S_ + q0 + qi * 32 + l31];

  const uint16_t* Erow =
      E + ((size_t)(b * S_ + q0 + qi * 32 + l31)) * 2048 + 8 * h;

  // prologue: stage xt tile 0 into buffer 0 + load E for kt=0
  bf16x8 bfrA[4], bfrB[4];
#pragma unroll
  for (int ks = 0; ks < 4; ++ks) bfrA[ks] = *(const bf16x8*)(Erow + 16 * ks);
#pragma unroll
  for (int i = 0; i < 8; ++i) {
    int d = wave * 64 + i * 8 + (lane >> 3);
    int gd = l7 ^ (d & 7);
    int p2 = (gd & ~3) | ((gd ^ (d & 3)) & 3);
    g2lds16((char*)xtlds[0] + (wave * 64 + i * 8) * 128,
            xtb + (size_t)d * 4096 + p2 * 16);
  }
  __syncthreads();

  f32x16 pv[8];
#pragma unroll
  for (int t = 0; t < 8; ++t) pv[t] = (f32x16){};

  for (int kt = 0; kt < 32; kt += 2) {
    PV_KT_BODY(kt, xtlds[0], xtlds[1], bfrA, bfrB);        // even kt
    PV_KT_BODY(kt + 1, xtlds[1], xtlds[0], bfrB, bfrA);    // odd kt
  }

  // epilogue: ctx via per-wave 4KB transpose stage (reuse xtlds), full lines.
  // FULLY unrolled: pv[t] statically indexed everywhere (rule #20).
  char* sbuf = (char*)xtlds[0] + wave * 4096;  // [32 q][32 d] f32, swz by q&7
#pragma unroll
  for (int t = 0; t < 8; ++t) {
#pragma unroll
    for (int rp = 0; rp < 8; ++rp) {
      int r = 2 * rp;
      int d0 = (r & 3) + 8 * (r >> 2) + 4 * h;
      int g = (d0 >> 2) ^ (l31 & 7);
      float2 v = make_float2(pv[t][r] * inv, pv[t][r + 1] * inv);
      *(float2*)(sbuf + l31 * 128 + g * 16 + (d0 & 3) * 4) = v;
    }
#pragma unroll
    for (int jj = 0; jj < 4; ++jj) {
      int row = jj * 8 + (lane >> 3);
      int g = l7 ^ (row & 7);
      f32x4 vv = *(const f32x4*)(sbuf + row * 128 + g * 16);
      *(f32x4*)(ctx + ((size_t)(b * S_ + q0 + qi * 32 + row)) * 512 +
                di * 256 + t * 32 + l7 * 4) = vv;
    }
  }
}

// ---------------------------------------------------------------------------
// Round-1 fused kernel, mid-tier fallback (known good).
// ---------------------------------------------------------------------------
__global__ __launch_bounds__(512, 2) void attn_main(
    const uint16_t* __restrict__ xbf, const uint16_t* __restrict__ xtr,
    float* __restrict__ ctx, float* __restrict__ wout) {
  __shared__ uint16_t klds[BN * D_];
  __shared__ uint16_t xtlds[D_ * BN];
  __shared__ uint16_t wlds[8][16][40];

  const int tid = threadIdx.x;
  const int wave = tid >> 6, lane = tid & 63;
  const int lg = lane >> 4, lr = lane & 15;
  const int bid = blockIdx.x;
  const int job = (bid & 7) * 32 + (bid >> 3);
  const int b = job >> 4;
  const int q0 = (job & 15) * BM;

  const char* xb = (const char*)(xbf + (size_t)b * S_ * D_);
  const char* xtb = (const char*)(xtr + (size_t)b * D_ * S_);

  const int qrow = q0 + wave * 16 + lr;
  bf16x8 qf[16];
#pragma unroll
  for (int c = 0; c < 16; ++c) {
    int g = (4 * c + lg) ^ (qrow & 7);
    qf[c] = *(const bf16x8*)(xb + (size_t)qrow * 1024 + g * 16);
  }

  float psum[4] = {0.f, 0.f, 0.f, 0.f};

  for (int kt = 0; kt < S_ / BN; ++kt) {
    const char* ksrc = xb + (size_t)kt * BN * 1024;
#pragma unroll
    for (int it = 0; it < 4; ++it) {
      int ob = it * 8192 + wave * 1024;
      g2lds16((char*)klds + ob, ksrc + ob + lane * 16);
    }
    __syncthreads();
    f32x4 acc0 = {0.f, 0.f, 0.f, 0.f}, acc1 = {0.f, 0.f, 0.f, 0.f};
#pragma unroll
    for (int c = 0; c < 16; ++c) {
      {
        int t = lr;
        int g = (4 * c + lg) ^ (t & 7);
        bf16x8 bf = *(const bf16x8*)((const char*)klds + t * 1024 + g * 16);
        acc0 = __builtin_amdgcn_mfma_f32_16x16x32_bf16(qf[c], bf, acc0, 0, 0, 0);
      }
      {
        int t = 16 + lr;
        int g = (4 * c + lg) ^ (t & 7);
        bf16x8 bf = *(const bf16x8*)((const char*)klds + t * 1024 + g * 16);
        acc1 = __builtin_amdgcn_mfma_f32_16x16x32_bf16(qf[c], bf, acc1, 0, 0, 0);
      }
    }
#pragma unroll
    for (int r = 0; r < 4; ++r) {
      float s0 = acc0[r] * SCALE;
      float s1 = acc1[r] * SCALE;
      psum[r] += (s0 > TAU ? __expf(s0) : 0.f) + (s1 > TAU ? __expf(s1) : 0.f);
    }
    __syncthreads();
  }

#pragma unroll
  for (int r = 0; r < 4; ++r) {
    float v = psum[r];
#pragma unroll
    for (int m = 1; m < 16; m <<= 1) v += __shfl_xor(v, m, 64);
    psum[r] = 1.f / v;
  }

  f32x4 pv[32];
  const f32x4 fz = {0.f, 0.f, 0.f, 0.f};
#pragma unroll
  for (int n = 0; n < 32; ++n) pv[n] = fz;

  for (int kt = 0; kt < S_ / BN; ++kt) {
    const char* ksrc = xb + (size_t)kt * BN * 1024;
#pragma unroll
    for (int it = 0; it < 4; ++it) {
      int ob = it * 8192 + wave * 1024;
      g2lds16((char*)klds + ob, ksrc + ob + lane * 16);
    }
#pragma unroll
    for (int it = 0; it < 4; ++it) {
      int ob = it * 8192 + wave * 1024;
      int o = ob + lane * 16;
      const char* src = xtb + (size_t)(o >> 6) * 4096 + kt * 64 + (o & 63);
      g2lds16((char*)xtlds + ob, src);
    }
    __syncthreads();

    f32x4 acc0 = {0.f, 0.f, 0.f, 0.f}, acc1 = {0.f, 0.f, 0.f, 0.f};
#pragma unroll
    for (int c = 0; c < 16; ++c) {
      {
        int t = lr;
        int g = (4 * c + lg) ^ (t & 7);
        bf16x8 bf = *(const bf16x8*)((const char*)klds + t * 1024 + g * 16);
        acc0 = __builtin_amdgcn_mfma_f32_16x16x32_bf16(qf[c], bf, acc0, 0, 0, 0);
      }
      {
        int t = 16 + lr;
        int g = (4 * c + lg) ^ (t & 7);
        bf16x8 bf = *(const bf16x8*)((const char*)klds + t * 1024 + g * 16);
        acc1 = __builtin_amdgcn_mfma_f32_16x16x32_bf16(qf[c], bf, acc1, 0, 0, 0);
      }
    }

#pragma unroll
    for (int j = 0; j < 2; ++j) {
      f32x4 a = j ? acc1 : acc0;
#pragma unroll
      for (int r = 0; r < 4; ++r) {
        float s = a[r] * SCALE;
        float w = (s > TAU) ? __expf(s) * psum[r] : 0.f;
        int ql = wave * 16 + 4 * lg + r;
        wout[((size_t)(b * S_ + q0 + ql)) * S_ + kt * BN + j * 16 + lr] = w;
        wlds[wave][4 * lg + r][j * 16 + lr] = f2bf(w);
      }
    }

    bf16x8 wa = *(const bf16x8*)((const char*)&wlds[wave][0][0] + lr * 80 + lg * 16);
#pragma unroll
    for (int n = 0; n < 32; ++n) {
      int d = n * 16 + lr;
      int g = lg ^ (d & 3);
      bf16x8 bf = *(const bf16x8*)((const char*)xtlds + d * 64 + g * 16);
      pv[n] = __builtin_amdgcn_mfma_f32_16x16x32_bf16(wa, bf, pv[n], 0, 0, 0);
    }
    __syncthreads();
  }

  const int qg = q0 + wave * 16 + 4 * lg;
#pragma unroll
  for (int n = 0; n < 32; ++n) {
#pragma unroll
    for (int r = 0; r < 4; ++r) {
      ctx[((size_t)(b * S_ + qg + r)) * D_ + n * 16 + lr] = pv[n][r];
    }
  }
}

// ---------------------------------------------------------------------------
// Naive fp32 fallback (tiny ws).
// ---------------------------------------------------------------------------
__global__ __launch_bounds__(256) void fb_weights(const float* __restrict__ x,
                                                  float* __restrict__ wout) {
  const int b = blockIdx.x >> 11;
  const int q = blockIdx.x & 2047;
  __shared__ float qv[512];
  __shared__ float red[256];
  const int tid = threadIdx.x;
  const float* xb = x + (size_t)b * S_ * D_;
  for (int d = tid; d < 512; d += 256) qv[d] = xb[(size_t)q * 512 + d];
  __syncthreads();
  float s[8];
  float lsum = 0.f;
#pragma unroll
  for (int i = 0; i < 8; ++i) {
    int k = i * 256 + tid;
    const float* xr = xb + (size_t)k * 512;
    float dot = 0.f;
    for (int d = 0; d < 512; ++d) dot += qv[d] * xr[d];
    dot *= SCALE;
    float e = (dot > TAU) ? __expf(dot) : 0.f;
    s[i] = e;
    lsum += e;
  }
  red[tid] = lsum;
  __syncthreads();
  for (int st = 128; st > 0; st >>= 1) {
    if (tid < st) red[tid] += red[tid + st];
    __syncthreads();
  }
  float inv = 1.f / red[0];
#pragma unroll
  for (int i = 0; i < 8; ++i)
    wout[((size_t)(b * S_ + q)) * S_ + i * 256 + tid] = s[i] * inv;
}

__global__ __launch_bounds__(256) void fb_ctx(const float* __restrict__ x,
                                              const float* __restrict__ wout,
                                              float* __restrict__ ctx) {
  const int b = blockIdx.x >> 11;
  const int q = blockIdx.x & 2047;
  const int tid = threadIdx.x;
  const float* xb = x + (size_t)b * S_ * D_;
  const float* wr = wout + ((size_t)(b * S_ + q)) * S_;
  float a0 = 0.f, a1 = 0.f;
  for (int k = 0; k < 2048; ++k) {
    float w = wr[k];
    a0 += w * xb[(size_t)k * 512 + tid];
    a1 += w * xb[(size_t)k * 512 + 256 + tid];
  }
  ctx[((size_t)(b * S_ + q)) * 512 + tid] = a0;
  ctx[((size_t)(b * S_ + q)) * 512 + 256 + tid] = a1;
}

// ---------------------------------------------------------------------------
extern "C" void kernel_launch(void* const* d_in, const int* in_sizes, int n_in,
                              void* d_out, int out_size, void* d_ws, size_t ws_size,
                              hipStream_t stream) {
  (void)in_sizes; (void)n_in; (void)out_size;
  const float* x = (const float*)d_in[0];
  float* ctx = (float*)d_out;
  float* wout = (float*)d_out + (size_t)B_ * S_ * D_;

  const size_t half = (size_t)B_ * S_ * D_ * 2;        // 32 MiB per bf16 copy
  const size_t e_bytes = (size_t)B_ * S_ * S_ * 2;     // 128 MiB
  const size_t psum_bytes = (size_t)B_ * S_ * 4;       // 128 KiB
  const size_t need_new = 2 * half + e_bytes + psum_bytes;

  if (ws_size >= need_new) {
    uint16_t* xbf = (uint16_t*)d_ws;
    uint16_t* xtr = (uint16_t*)((char*)d_ws + half);
    uint16_t* E = (uint16_t*)((char*)d_ws + 2 * half);
    float* psum_g = (float*)((char*)d_ws + 2 * half + e_bytes);
    convert_kernel<<<dim3(4096), dim3(256), 0, stream>>>(x, xbf, xtr);
    attn_scores<<<dim3(256), dim3(512), 0, stream>>>(xbf, E, psum_g);
    attn_pv14<<<dim3(256), dim3(512), 0, stream>>>(E, xtr, psum_g, ctx, wout);
  } else if (ws_size >= 2 * half) {
    uint16_t* xbf = (uint16_t*)d_ws;
    uint16_t* xtr = (uint16_t*)((char*)d_ws + half);
    convert_kernel<<<dim3(4096), dim3(256), 0, stream>>>(x, xbf, xtr);
    attn_main<<<dim3(256), dim3(512), 0, stream>>>(xbf, xtr, ctx, wout);
  } else {
    fb_weights<<<dim3(32768), dim3(256), 0, stream>>>(x, wout);
    fb_ctx<<<dim3(32768), dim3(256), 0, stream>>>(x, wout, ctx);
  }
}

// Round 15
// 273.061 us; speedup vs baseline: 1.0392x; 1.0392x over previous
//
#include <hip/hip_runtime.h>
#include <hip/hip_bf16.h>
#include <stdint.h>

#define B_ 16
#define S_ 2048
#define D_ 512
#define TAU 0.1f
#define SCALE 0.04419417382415922f   // 1/sqrt(512)
#define BM 128
#define BN 32

typedef __attribute__((ext_vector_type(8))) __bf16 bf16x8;
typedef __attribute__((ext_vector_type(4))) float f32x4;
typedef __attribute__((ext_vector_type(16))) float f32x16;
typedef __attribute__((ext_vector_type(8))) uint16_t u16x8;
typedef __attribute__((ext_vector_type(4))) uint16_t u16x4;

__device__ __forceinline__ uint16_t f2bf(float f) {
  __hip_bfloat16 h = __float2bfloat16(f);
  return __builtin_bit_cast(uint16_t, h);
}

__device__ __forceinline__ float bf2f(uint16_t u) {
  return __uint_as_float(((uint32_t)u) << 16);
}

__device__ __forceinline__ void g2lds16(void* lds, const void* g) {
  __builtin_amdgcn_global_load_lds(
      (const __attribute__((address_space(1))) unsigned int*)g,
      (__attribute__((address_space(3))) unsigned int*)lds, 16, 0, 0);
}

// ---------------------------------------------------------------------------
// Convert fp32 x -> bf16 copies in ws (unchanged):
//  xbf[b][t][d]  row-major, 16B-granule index XOR-swizzled by (t&7)
//  xt [b][d][t]  row-major in t, granule low-2-bits XOR-swizzled by (d&3)
// ---------------------------------------------------------------------------
__global__ __launch_bounds__(256) void convert_kernel(
    const float* __restrict__ x, uint16_t* __restrict__ xbf,
    uint16_t* __restrict__ xt) {
  const int bid = blockIdx.x;
  const int b = bid >> 8;
  const int tt = (bid >> 3) & 31;
  const int dt = bid & 7;
  const int t0 = tt * 64, d0 = dt * 64;
  __shared__ uint16_t tile[64][72];
  const int tid = threadIdx.x;
  const float* xb = x + ((size_t)b * S_ + t0) * D_ + d0;

#pragma unroll
  for (int it = 0; it < 4; ++it) {
    int r = it * 16 + (tid >> 4);
    int c = (tid & 15) * 4;
    float4 v = *(const float4*)(xb + (size_t)r * D_ + c);
    tile[r][c + 0] = f2bf(v.x);
    tile[r][c + 1] = f2bf(v.y);
    tile[r][c + 2] = f2bf(v.z);
    tile[r][c + 3] = f2bf(v.w);
  }
  __syncthreads();

#pragma unroll
  for (int it = 0; it < 2; ++it) {
    int G = it * 256 + tid;
    int tl = G >> 3, gl = G & 7;
    int t = t0 + tl;
    int p = (d0 >> 3) + (gl ^ (t & 7));
    u16x8 v = *(const u16x8*)&tile[tl][gl * 8];
    *(u16x8*)((char*)xbf + (size_t)(b * S_ + t) * 1024 + p * 16) = v;
  }
#pragma unroll
  for (int it = 0; it < 2; ++it) {
    int G = it * 256 + tid;
    int dl = G >> 3, gl = G & 7;
    int d = d0 + dl;
    int p = (gl & ~3) | ((gl ^ (d & 3)) & 3);
    u16x8 v;
#pragma unroll
    for (int i = 0; i < 8; ++i) v[i] = tile[gl * 8 + i][dl];
    *(u16x8*)((char*)xt + (size_t)(b * D_ + d) * 4096 + t0 * 2 + p * 16) = v;
  }
}

// ---------------------------------------------------------------------------
// Kernel A v15 = round-6 scores with ONE change: E stored via wave-local LDS
// re-lane (full 64B half-lines, 2 instrs x 16 rows x 64B per wave-kt) instead
// of 4 scattered 16B/row stores (1024 -> 256 L2 store transactions per CU-kt;
// calibration: pv11-vs-pv10 measured 2.3cy/transaction). Wave-local slice,
// within-wave write->read (lgkmcnt only, no new barrier — pv14-proven safe).
// 8B chunks XOR-swizzled by row&7 (G4). All MFMA/fragment math unchanged.
// ---------------------------------------------------------------------------
__global__ __launch_bounds__(512, 2) void attn_scores15(
    const uint16_t* __restrict__ xbf, uint16_t* __restrict__ E,
    float* __restrict__ psum_g) {
  __shared__ uint16_t klds[2][64 * 512];   // 2 x 64KB swizzled K-tile images
  __shared__ uint16_t estage[8 * 32 * 32]; // 16KB: per-wave 2KB E tile
  __shared__ float redbuf[4 * 2 * 32];

  const int tid = threadIdx.x;
  const int wave = tid >> 6, lane = tid & 63;
  const int h = lane >> 5, l31 = lane & 31, l7 = lane & 7;
  const int qi = wave >> 1, ki = wave & 1;
  const int bid = blockIdx.x;
  const int job = (bid & 7) * 32 + (bid >> 3);
  const int b = job >> 4;
  const int q0 = (job & 15) * BM;

  const char* xb = (const char*)xbf + (size_t)b * S_ * 1024;
  char* esl = (char*)estage + wave * 2048;

  const size_t qrow = (size_t)(q0 + qi * 32 + l31);
  bf16x8 qf[32];
#pragma unroll
  for (int s = 0; s < 32; ++s) {
    int g = (2 * s + h) ^ l7;  // qrow&7 == l7
    qf[s] = *(const bf16x8*)(xb + qrow * 1024 + g * 16);
  }

  float psum = 0.f;

  // prologue: stage tile 0
#pragma unroll
  for (int i = 0; i < 8; ++i) {
    int row = wave * 8 + i;
    g2lds16((char*)klds[0] + row * 1024, xb + (size_t)row * 1024 + lane * 16);
  }
  __syncthreads();

  for (int kt = 0; kt < 32; ++kt) {
    const int cur = kt & 1;
    const char* kldsc = (const char*)klds[cur];

    if (kt < 31) {
#pragma unroll
      for (int i = 0; i < 8; ++i) {
        int row = wave * 8 + i;
        g2lds16((char*)klds[cur ^ 1] + row * 1024,
                xb + (size_t)((kt + 1) * 64 + row) * 1024 + lane * 16);
      }
    }

    f32x16 acc = {};
#pragma unroll
    for (int s = 0; s < 32; ++s) {
      int g = (2 * s + h) ^ l7;  // klocal&7 == l7
      bf16x8 af = *(const bf16x8*)(kldsc + (size_t)(ki * 32 + l31) * 1024 + g * 16);
      acc = __builtin_amdgcn_mfma_f32_32x32x16_bf16(af, qf[s], acc, 0, 0, 0);
    }

    // E = exp(masked score): stage wave's 32q x 32k tile in LDS (8B chunks,
    // chunk j = h + 2*q4 covers k-local 4j..4j+3; position j ^ (row&7)).
    // acc[r]: q=l31 (row), k-local = (r&3) + 8*(r>>2) + 4h.
#pragma unroll
    for (int q4 = 0; q4 < 4; ++q4) {
      u16x4 w4;
#pragma unroll
      for (int j = 0; j < 4; ++j) {
        float s = acc[4 * q4 + j] * SCALE;
        float e = (s > TAU) ? __expf(s) : 0.f;
        psum += e;
        w4[j] = f2bf(e);
      }
      int jc = h + 2 * q4;
      *(u16x4*)(esl + l31 * 64 + ((jc ^ l7) * 8)) = w4;
    }

    // re-laned readback + full 64B half-line stores: 16 rows x 64B per instr
#pragma unroll
    for (int jj = 0; jj < 2; ++jj) {
      int r = jj * 16 + (lane >> 2);
      int p = lane & 3;
      u16x4 lo = *(const u16x4*)(esl + r * 64 + (((2 * p) ^ (r & 7)) * 8));
      u16x4 hi = *(const u16x4*)(esl + r * 64 + (((2 * p + 1) ^ (r & 7)) * 8));
      u16x8 v;
#pragma unroll
      for (int i = 0; i < 4; ++i) { v[i] = lo[i]; v[4 + i] = hi[i]; }
      *(u16x8*)(E + ((size_t)b * S_ + q0 + qi * 32 + r) * 2048 + kt * 64 +
                ki * 32 + 8 * p) = v;
    }
    __syncthreads();
  }

  psum += __shfl_xor(psum, 32, 64);
  if (lane < 32) redbuf[qi * 64 + ki * 32 + lane] = psum;
  __syncthreads();
  if (ki == 0 && lane < 32) {
    float tot = redbuf[qi * 64 + lane] + redbuf[qi * 64 + 32 + lane];
    psum_g[(size_t)b * S_ + q0 + qi * 32 + lane] = tot;
  }
}

// ---------------------------------------------------------------------------
// Kernel B v10 (best measured pv, ~170us — round-13 verbatim): pv3 +
// E-register double-buffer; wstage full-line W path (load-bearing).
// Waves: qi = wave>>1 (4 q-groups of 32), di = wave&1 (2 d-halves of 256).
// ---------------------------------------------------------------------------
#define PV_KT_BODY(KT, XCUR, XNXT, BCUR, BNXT)                                  \
  do {                                                                          \
    if ((KT) < 31) {                                                            \
      /* prefetch next-kt E fragments (consumed next body) */                   \
      _Pragma("unroll") for (int ks = 0; ks < 4; ++ks)                          \
          BNXT[ks] = *(const bf16x8*)(Erow + ((KT) + 1) * 64 + 16 * ks);        \
      /* stage next xt tile into the other buffer */                            \
      _Pragma("unroll") for (int i = 0; i < 8; ++i) {                           \
        int d = wave * 64 + i * 8 + (lane >> 3);                                \
        int gd = l7 ^ (d & 7);                                                  \
        int p2 = (gd & ~3) | ((gd ^ (d & 3)) & 3);                              \
        g2lds16((char*)(XNXT) + (wave * 64 + i * 8) * 128,                      \
                xtb + (size_t)d * 4096 + ((KT) + 1) * 128 + p2 * 16);           \
      }                                                                         \
    }                                                                           \
    /* PV MFMAs: A = X^T[32d x 16k] from LDS, B = BCUR (prefetched) */          \
    _Pragma("unroll") for (int t = 0; t < 8; ++t) {                             \
      int dl = di * 256 + t * 32 + l31;                                         \
      _Pragma("unroll") for (int ks = 0; ks < 4; ++ks) {                        \
        int slot = (2 * ks + h) ^ (dl & 7);                                     \
        bf16x8 af =                                                             \
            *(const bf16x8*)((const char*)(XCUR) + (size_t)dl * 128 + slot * 16);\
        pv[t] = __builtin_amdgcn_mfma_f32_32x32x16_bf16(af, BCUR[ks], pv[t],    \
                                                        0, 0, 0);               \
      }                                                                         \
    }                                                                           \
    /* stage E (bf16) into wstage for W re-laning (di==0 waves only) */         \
    if (di == 0) {                                                              \
      int q = qi * 32 + l31;                                                    \
      _Pragma("unroll") for (int ks = 0; ks < 4; ++ks) {                        \
        int g = (2 * ks + h) ^ (q & 7);                                         \
        *(u16x8*)(wstc + q * 128 + g * 16) = __builtin_bit_cast(u16x8, BCUR[ks]);\
      }                                                                         \
    }                                                                           \
    __syncthreads();                                                            \
    /* W = E*inv -> global; per instr: 8 rows x 128B full lines */              \
    _Pragma("unroll") for (int j = 0; j < 2; ++j) {                             \
      int row = wave * 16 + j * 8 + (lane >> 3);                                \
      float invq = invlds[row];                                                 \
      _Pragma("unroll") for (int hf = 0; hf < 2; ++hf) {                        \
        int g = (hf * 4 + (l7 >> 1)) ^ (row & 7);                               \
        u16x4 ev = *(const u16x4*)(wstc + row * 128 + g * 16 + (l7 & 1) * 8);   \
        f32x4 w;                                                                \
        _Pragma("unroll") for (int i2 = 0; i2 < 4; ++i2)                        \
            w[i2] = bf2f(ev[i2]) * invq;                                        \
        *(f32x4*)(wout + ((size_t)(b * S_ + q0 + row)) * 2048 + (KT) * 64 +     \
                  hf * 32 + l7 * 4) = w;                                        \
      }                                                                         \
    }                                                                           \
    __syncthreads();                                                            \
  } while (0)

__global__ __launch_bounds__(512) void attn_pv10(
    const uint16_t* __restrict__ E, const uint16_t* __restrict__ xt,
    const float* __restrict__ psum_g, float* __restrict__ ctx,
    float* __restrict__ wout) {
  __shared__ uint16_t xtlds[2][512 * 64];  // 2 x 64KB, granule-swizzled by d&7
  __shared__ uint16_t wstage[128 * 64];    // 16KB bf16 E tile, swizzled by q&7
  __shared__ float invlds[128];

  const int tid = threadIdx.x;
  const int wave = tid >> 6, lane = tid & 63;
  const int h = lane >> 5, l31 = lane & 31, l7 = lane & 7;
  const int qi = wave >> 1, di = wave & 1;
  const int bid = blockIdx.x;
  const int job = (bid & 7) * 32 + (bid >> 3);
  const int b = job >> 4;
  const int q0 = (job & 15) * BM;

  const char* xtb = (const char*)xt + (size_t)b * D_ * 4096;
  char* wstc = (char*)wstage;

  const float inv = 1.0f / psum_g[(size_t)b * S_ + q0 + qi * 32 + l31];
  if (tid < 128) invlds[tid] = 1.0f / psum_g[(size_t)b * S_ + q0 + tid];

  const uint16_t* Erow =
      E + ((size_t)(b * S_ + q0 + qi * 32 + l31)) * 2048 + 8 * h;

  // prologue: stage xt tile 0 into buffer 0 + load E for kt=0
  bf16x8 bfrA[4], bfrB[4];
#pragma unroll
  for (int ks = 0; ks < 4; ++ks) bfrA[ks] = *(const bf16x8*)(Erow + 16 * ks);
#pragma unroll
  for (int i = 0; i < 8; ++i) {
    int d = wave * 64 + i * 8 + (lane >> 3);
    int gd = l7 ^ (d & 7);
    int p2 = (gd & ~3) | ((gd ^ (d & 3)) & 3);
    g2lds16((char*)xtlds[0] + (wave * 64 + i * 8) * 128,
            xtb + (size_t)d * 4096 + p2 * 16);
  }
  __syncthreads();

  f32x16 pv[8];
#pragma unroll
  for (int t = 0; t < 8; ++t) pv[t] = (f32x16){};

  for (int kt = 0; kt < 32; kt += 2) {
    PV_KT_BODY(kt, xtlds[0], xtlds[1], bfrA, bfrB);        // even kt
    PV_KT_BODY(kt + 1, xtlds[1], xtlds[0], bfrB, bfrA);    // odd kt
  }

  // epilogue: ctx via per-wave 4KB transpose stage (reuse xtlds), full lines.
  // FULLY unrolled: pv[t] statically indexed everywhere (rule #20).
  char* sbuf = (char*)xtlds[0] + wave * 4096;  // [32 q][32 d] f32, swz by q&7
#pragma unroll
  for (int t = 0; t < 8; ++t) {
#pragma unroll
    for (int rp = 0; rp < 8; ++rp) {
      int r = 2 * rp;
      int d0 = (r & 3) + 8 * (r >> 2) + 4 * h;
      int g = (d0 >> 2) ^ (l31 & 7);
      float2 v = make_float2(pv[t][r] * inv, pv[t][r + 1] * inv);
      *(float2*)(sbuf + l31 * 128 + g * 16 + (d0 & 3) * 4) = v;
    }
#pragma unroll
    for (int jj = 0; jj < 4; ++jj) {
      int row = jj * 8 + (lane >> 3);
      int g = l7 ^ (row & 7);
      f32x4 vv = *(const f32x4*)(sbuf + row * 128 + g * 16);
      *(f32x4*)(ctx + ((size_t)(b * S_ + q0 + qi * 32 + row)) * 512 +
                di * 256 + t * 32 + l7 * 4) = vv;
    }
  }
}

// ---------------------------------------------------------------------------
// Round-1 fused kernel, mid-tier fallback (known good).
// ---------------------------------------------------------------------------
__global__ __launch_bounds__(512, 2) void attn_main(
    const uint16_t* __restrict__ xbf, const uint16_t* __restrict__ xtr,
    float* __restrict__ ctx, float* __restrict__ wout) {
  __shared__ uint16_t klds[BN * D_];
  __shared__ uint16_t xtlds[D_ * BN];
  __shared__ uint16_t wlds[8][16][40];

  const int tid = threadIdx.x;
  const int wave = tid >> 6, lane = tid & 63;
  const int lg = lane >> 4, lr = lane & 15;
  const int bid = blockIdx.x;
  const int job = (bid & 7) * 32 + (bid >> 3);
  const int b = job >> 4;
  const int q0 = (job & 15) * BM;

  const char* xb = (const char*)(xbf + (size_t)b * S_ * D_);
  const char* xtb = (const char*)(xtr + (size_t)b * D_ * S_);

  const int qrow = q0 + wave * 16 + lr;
  bf16x8 qf[16];
#pragma unroll
  for (int c = 0; c < 16; ++c) {
    int g = (4 * c + lg) ^ (qrow & 7);
    qf[c] = *(const bf16x8*)(xb + (size_t)qrow * 1024 + g * 16);
  }

  float psum[4] = {0.f, 0.f, 0.f, 0.f};

  for (int kt = 0; kt < S_ / BN; ++kt) {
    const char* ksrc = xb + (size_t)kt * BN * 1024;
#pragma unroll
    for (int it = 0; it < 4; ++it) {
      int ob = it * 8192 + wave * 1024;
      g2lds16((char*)klds + ob, ksrc + ob + lane * 16);
    }
    __syncthreads();
    f32x4 acc0 = {0.f, 0.f, 0.f, 0.f}, acc1 = {0.f, 0.f, 0.f, 0.f};
#pragma unroll
    for (int c = 0; c < 16; ++c) {
      {
        int t = lr;
        int g = (4 * c + lg) ^ (t & 7);
        bf16x8 bf = *(const bf16x8*)((const char*)klds + t * 1024 + g * 16);
        acc0 = __builtin_amdgcn_mfma_f32_16x16x32_bf16(qf[c], bf, acc0, 0, 0, 0);
      }
      {
        int t = 16 + lr;
        int g = (4 * c + lg) ^ (t & 7);
        bf16x8 bf = *(const bf16x8*)((const char*)klds + t * 1024 + g * 16);
        acc1 = __builtin_amdgcn_mfma_f32_16x16x32_bf16(qf[c], bf, acc1, 0, 0, 0);
      }
    }
#pragma unroll
    for (int r = 0; r < 4; ++r) {
      float s0 = acc0[r] * SCALE;
      float s1 = acc1[r] * SCALE;
      psum[r] += (s0 > TAU ? __expf(s0) : 0.f) + (s1 > TAU ? __expf(s1) : 0.f);
    }
    __syncthreads();
  }

#pragma unroll
  for (int r = 0; r < 4; ++r) {
    float v = psum[r];
#pragma unroll
    for (int m = 1; m < 16; m <<= 1) v += __shfl_xor(v, m, 64);
    psum[r] = 1.f / v;
  }

  f32x4 pv[32];
  const f32x4 fz = {0.f, 0.f, 0.f, 0.f};
#pragma unroll
  for (int n = 0; n < 32; ++n) pv[n] = fz;

  for (int kt = 0; kt < S_ / BN; ++kt) {
    const char* ksrc = xb + (size_t)kt * BN * 1024;
#pragma unroll
    for (int it = 0; it < 4; ++it) {
      int ob = it * 8192 + wave * 1024;
      g2lds16((char*)klds + ob, ksrc + ob + lane * 16);
    }
#pragma unroll
    for (int it = 0; it < 4; ++it) {
      int ob = it * 8192 + wave * 1024;
      int o = ob + lane * 16;
      const char* src = xtb + (size_t)(o >> 6) * 4096 + kt * 64 + (o & 63);
      g2lds16((char*)xtlds + ob, src);
    }
    __syncthreads();

    f32x4 acc0 = {0.f, 0.f, 0.f, 0.f}, acc1 = {0.f, 0.f, 0.f, 0.f};
#pragma unroll
    for (int c = 0; c < 16; ++c) {
      {
        int t = lr;
        int g = (4 * c + lg) ^ (t & 7);
        bf16x8 bf = *(const bf16x8*)((const char*)klds + t * 1024 + g * 16);
        acc0 = __builtin_amdgcn_mfma_f32_16x16x32_bf16(qf[c], bf, acc0, 0, 0, 0);
      }
      {
        int t = 16 + lr;
        int g = (4 * c + lg) ^ (t & 7);
        bf16x8 bf = *(const bf16x8*)((const char*)klds + t * 1024 + g * 16);
        acc1 = __builtin_amdgcn_mfma_f32_16x16x32_bf16(qf[c], bf, acc1, 0, 0, 0);
      }
    }

#pragma unroll
    for (int j = 0; j < 2; ++j) {
      f32x4 a = j ? acc1 : acc0;
#pragma unroll
      for (int r = 0; r < 4; ++r) {
        float s = a[r] * SCALE;
        float w = (s > TAU) ? __expf(s) * psum[r] : 0.f;
        int ql = wave * 16 + 4 * lg + r;
        wout[((size_t)(b * S_ + q0 + ql)) * S_ + kt * BN + j * 16 + lr] = w;
        wlds[wave][4 * lg + r][j * 16 + lr] = f2bf(w);
      }
    }

    bf16x8 wa = *(const bf16x8*)((const char*)&wlds[wave][0][0] + lr * 80 + lg * 16);
#pragma unroll
    for (int n = 0; n < 32; ++n) {
      int d = n * 16 + lr;
      int g = lg ^ (d & 3);
      bf16x8 bf = *(const bf16x8*)((const char*)xtlds + d * 64 + g * 16);
      pv[n] = __builtin_amdgcn_mfma_f32_16x16x32_bf16(wa, bf, pv[n], 0, 0, 0);
    }
    __syncthreads();
  }

  const int qg = q0 + wave * 16 + 4 * lg;
#pragma unroll
  for (int n = 0; n < 32; ++n) {
#pragma unroll
    for (int r = 0; r < 4; ++r) {
      ctx[((size_t)(b * S_ + qg + r)) * D_ + n * 16 + lr] = pv[n][r];
    }
  }
}

// ---------------------------------------------------------------------------
// Naive fp32 fallback (tiny ws).
// ---------------------------------------------------------------------------
__global__ __launch_bounds__(256) void fb_weights(const float* __restrict__ x,
                                                  float* __restrict__ wout) {
  const int b = blockIdx.x >> 11;
  const int q = blockIdx.x & 2047;
  __shared__ float qv[512];
  __shared__ float red[256];
  const int tid = threadIdx.x;
  const float* xb = x + (size_t)b * S_ * D_;
  for (int d = tid; d < 512; d += 256) qv[d] = xb[(size_t)q * 512 + d];
  __syncthreads();
  float s[8];
  float lsum = 0.f;
#pragma unroll
  for (int i = 0; i < 8; ++i) {
    int k = i * 256 + tid;
    const float* xr = xb + (size_t)k * 512;
    float dot = 0.f;
    for (int d = 0; d < 512; ++d) dot += qv[d] * xr[d];
    dot *= SCALE;
    float e = (dot > TAU) ? __expf(dot) : 0.f;
    s[i] = e;
    lsum += e;
  }
  red[tid] = lsum;
  __syncthreads();
  for (int st = 128; st > 0; st >>= 1) {
    if (tid < st) red[tid] += red[tid + st];
    __syncthreads();
  }
  float inv = 1.f / red[0];
#pragma unroll
  for (int i = 0; i < 8; ++i)
    wout[((size_t)(b * S_ + q)) * S_ + i * 256 + tid] = s[i] * inv;
}

__global__ __launch_bounds__(256) void fb_ctx(const float* __restrict__ x,
                                              const float* __restrict__ wout,
                                              float* __restrict__ ctx) {
  const int b = blockIdx.x >> 11;
  const int q = blockIdx.x & 2047;
  const int tid = threadIdx.x;
  const float* xb = x + (size_t)b * S_ * D_;
  const float* wr = wout + ((size_t)(b * S_ + q)) * S_;
  float a0 = 0.f, a1 = 0.f;
  for (int k = 0; k < 2048; ++k) {
    float w = wr[k];
    a0 += w * xb[(size_t)k * 512 + tid];
    a1 += w * xb[(size_t)k * 512 + 256 + tid];
  }
  ctx[((size_t)(b * S_ + q)) * 512 + tid] = a0;
  ctx[((size_t)(b * S_ + q)) * 512 + 256 + tid] = a1;
}

// ---------------------------------------------------------------------------
extern "C" void kernel_launch(void* const* d_in, const int* in_sizes, int n_in,
                              void* d_out, int out_size, void* d_ws, size_t ws_size,
                              hipStream_t stream) {
  (void)in_sizes; (void)n_in; (void)out_size;
  const float* x = (const float*)d_in[0];
  float* ctx = (float*)d_out;
  float* wout = (float*)d_out + (size_t)B_ * S_ * D_;

  const size_t half = (size_t)B_ * S_ * D_ * 2;        // 32 MiB per bf16 copy
  const size_t e_bytes = (size_t)B_ * S_ * S_ * 2;     // 128 MiB
  const size_t psum_bytes = (size_t)B_ * S_ * 4;       // 128 KiB
  const size_t need_new = 2 * half + e_bytes + psum_bytes;

  if (ws_size >= need_new) {
    uint16_t* xbf = (uint16_t*)d_ws;
    uint16_t* xtr = (uint16_t*)((char*)d_ws + half);
    uint16_t* E = (uint16_t*)((char*)d_ws + 2 * half);
    float* psum_g = (float*)((char*)d_ws + 2 * half + e_bytes);
    convert_kernel<<<dim3(4096), dim3(256), 0, stream>>>(x, xbf, xtr);
    attn_scores15<<<dim3(256), dim3(512), 0, stream>>>(xbf, E, psum_g);
    attn_pv10<<<dim3(256), dim3(512), 0, stream>>>(E, xtr, psum_g, ctx, wout);
  } else if (ws_size >= 2 * half) {
    uint16_t* xbf = (uint16_t*)d_ws;
    uint16_t* xtr = (uint16_t*)((char*)d_ws + half);
    convert_kernel<<<dim3(4096), dim3(256), 0, stream>>>(x, xbf, xtr);
    attn_main<<<dim3(256), dim3(512), 0, stream>>>(xbf, xtr, ctx, wout);
  } else {
    fb_weights<<<dim3(32768), dim3(256), 0, stream>>>(x, wout);
    fb_ctx<<<dim3(32768), dim3(256), 0, stream>>>(x, wout, ctx);
  }
}